// Round 6
// baseline (463.372 us; speedup 1.0000x reference)
//
#include <hip/hip_runtime.h>
#include <hip/hip_bf16.h>

#define NUM_E 64
#define D_K 512
#define D_N 512
#define BM 128
#define BN 128
#define MAX_TILES 576              // T/BM + E worst case
#define GRID_X (MAX_TILES * 4)     // 2304, divisible by 8 -> bijective XCD swizzle

typedef __bf16 bf16x8 __attribute__((ext_vector_type(8)));
typedef float f32x16 __attribute__((ext_vector_type(16)));
typedef float f32x4 __attribute__((ext_vector_type(4)));
typedef unsigned int u32;
typedef unsigned short u16;

__device__ __forceinline__ int imin(int a, int b) { return a < b ? a : b; }

// async global->LDS, 16B per lane. LDS dest must be wave-uniform base.
__device__ __forceinline__ void gll16(const void* g, void* l) {
    __builtin_amdgcn_global_load_lds(
        (const __attribute__((address_space(1))) u32*)(uintptr_t)g,
        (__attribute__((address_space(3))) u32*)(uintptr_t)l, 16, 0, 0);
}

// fp32 -> bf16 hi (round-nearest-even) + bf16 lo (truncated residual).
// IDENTICAL bits to rounds 1-4 (passed at absmax 0.015625) — do not change.
__device__ __forceinline__ void cvt_split(float a, u32 &hi, u32 &lo) {
    u32 u  = __float_as_uint(a);
    u32 rh = (u + 0x7FFFu + ((u >> 16) & 1u)) & 0xFFFF0000u;
    hi = rh >> 16;
    float res = a - __uint_as_float(rh);
    lo = __float_as_uint(res) >> 16;
}

// ---------------- tile descriptors (no tile crosses a group boundary) -------
__global__ void build_tiles_kernel(const int* __restrict__ gs,
                                   int* __restrict__ cnt,
                                   int* __restrict__ desc) {
    int e = threadIdx.x;
    if (e >= NUM_E) return;
    int row = 0, toff = 0;
    for (int i = 0; i < e; ++i) {
        int g = gs[i];
        row += g;
        toff += (g + BM - 1) / BM;
    }
    int g = gs[e];
    int nt = (g + BM - 1) / BM;
    for (int i = 0; i < nt; ++i) {
        int b = 3 * (toff + i);
        desc[b]     = e;
        desc[b + 1] = row + i * BM;
        desc[b + 2] = imin(BM, g - i * BM);
    }
    if (e == NUM_E - 1) cnt[0] = toff + nt;
}

// ------- convert X: [T][512] f32 -> [T][1024] bf16 (hi | lo), 16B stores ----
__global__ void convert_x_kernel(const float* __restrict__ X, u16* __restrict__ Xc,
                                 int nocts) {
    int idx = blockIdx.x * blockDim.x + threadIdx.x;
    int stride = gridDim.x * blockDim.x;
    for (int o = idx; o < nocts; o += stride) {
        int row = o >> 6;            // 64 octs (of 8 floats) per 512-float row
        int c8  = (o & 63) * 8;
        const float* p = X + (size_t)o * 8;
        f32x4 v0 = *(const f32x4*)p;
        f32x4 v1 = *(const f32x4*)(p + 4);
        u32 h[8], l[8];
        #pragma unroll
        for (int j = 0; j < 4; ++j) cvt_split(v0[j], h[j], l[j]);
        #pragma unroll
        for (int j = 0; j < 4; ++j) cvt_split(v1[j], h[4 + j], l[4 + j]);
        uint4 hp, lp;
        hp.x = h[0] | (h[1] << 16); hp.y = h[2] | (h[3] << 16);
        hp.z = h[4] | (h[5] << 16); hp.w = h[6] | (h[7] << 16);
        lp.x = l[0] | (l[1] << 16); lp.y = l[2] | (l[3] << 16);
        lp.z = l[4] | (l[5] << 16); lp.w = l[6] | (l[7] << 16);
        *(uint4*)(Xc + (size_t)row * 1024 + c8)       = hp;
        *(uint4*)(Xc + (size_t)row * 1024 + 512 + c8) = lp;
    }
}

// -- convert+transpose W: [e][k][n] f32 -> [e][n][1024] bf16 (hi | lo) -------
// f32 LDS transpose (ds_read_b128 on read side), 16B packed stores.
__global__ void convert_w_kernel(const float* __restrict__ W, u16* __restrict__ Wc) {
    __shared__ float Tf[64 * 68];    // [n][k], stride 68 (272B = 17x16B aligned)
    int bid = blockIdx.x;            // 64e x 8ti x 8tj = 4096
    int e  = bid >> 6;
    int ti = (bid >> 3) & 7;         // k-block
    int tj = bid & 7;                // n-block
    int tid = threadIdx.x;

    const float* Wp = W + (size_t)e * D_K * D_N + (size_t)(ti * 64) * D_N + tj * 64;
    #pragma unroll
    for (int it = 0; it < 4; ++it) {
        int kl = it * 16 + (tid >> 4);       // 0..63
        int nl = (tid & 15) * 4;             // 0..60
        f32x4 v = *(const f32x4*)(Wp + (size_t)kl * D_N + nl);
        #pragma unroll
        for (int j = 0; j < 4; ++j) Tf[(nl + j) * 68 + kl] = v[j];
    }
    __syncthreads();
    #pragma unroll
    for (int it = 0; it < 2; ++it) {
        int nl = it * 32 + (tid >> 3);       // 0..63
        int ko = (tid & 7) * 8;              // 0..56, 8 k's each
        f32x4 a = *(const f32x4*)(Tf + nl * 68 + ko);
        f32x4 b = *(const f32x4*)(Tf + nl * 68 + ko + 4);
        u32 h[8], l[8];
        #pragma unroll
        for (int j = 0; j < 4; ++j) cvt_split(a[j], h[j], l[j]);
        #pragma unroll
        for (int j = 0; j < 4; ++j) cvt_split(b[j], h[4 + j], l[4 + j]);
        uint4 hp, lp;
        hp.x = h[0] | (h[1] << 16); hp.y = h[2] | (h[3] << 16);
        hp.z = h[4] | (h[5] << 16); hp.w = h[6] | (h[7] << 16);
        lp.x = l[0] | (l[1] << 16); lp.y = l[2] | (l[3] << 16);
        lp.z = l[4] | (l[5] << 16); lp.w = l[6] | (l[7] << 16);
        u16* outp = Wc + ((size_t)e << 19) + (size_t)(tj * 64 + nl) * 1024 + ti * 64 + ko;
        *(uint4*)outp         = hp;
        *(uint4*)(outp + 512) = lp;
    }
}

// ------- main GEMM: bf16, K' = 1536, double-buffered LDS + counted vmcnt ----
__global__ void __launch_bounds__(256, 2)
gemm_split_kernel(const u16* __restrict__ Xc, const u16* __restrict__ Wc,
                  const float* __restrict__ bias, const int* __restrict__ cnt,
                  const int* __restrict__ desc, float* __restrict__ out, int T) {
    __shared__ u16 As[2][BM * 64];   // 2 x 16 KB, linear, XOR-swizzled content
    __shared__ u16 Bs[2][BN * 64];

    int bid = blockIdx.x;
    int s = (bid & 7) * (GRID_X / 8) + (bid >> 3);   // bijective XCD swizzle
    int tile  = s >> 2;
    int ntile = s & 3;
    if (tile >= cnt[0]) return;

    int expert = desc[3 * tile];
    int row0   = desc[3 * tile + 1];
    int rows   = desc[3 * tile + 2];
    int n0 = ntile * BN;

    const int tid  = threadIdx.x;
    const int lane = tid & 63;
    const int wid  = tid >> 6;
    const int wm = wid >> 1, wn = wid & 1;
    const int lr = lane & 31, kg = lane >> 5;

    // staging geometry: chunk = c*256 + tid; row = chunk>>3; j = chunk&7
    // LDS stays linear; SOURCE byte-in-row is XOR-swizzled (rule #21).
    int aoff[4], boff[4], ldsb[4];
    #pragma unroll
    for (int c = 0; c < 4; ++c) {
        int chunk = c * 256 + tid;
        int r = chunk >> 3, j = chunk & 7;
        int cb = (j * 16) ^ ((r & 7) << 4);          // swizzled source byte-in-row
        int ar = imin(row0 + r, T - 1);              // clamp (padded tail rows)
        aoff[c] = ar * 1024 + (cb >> 1);
        boff[c] = (expert << 19) + (n0 + r) * 1024 + (cb >> 1);
        ldsb[c] = (c * 256 + wid * 64) * 16;         // wave-uniform byte base in buf
    }

    f32x16 acc[2][2];
    #pragma unroll
    for (int i = 0; i < 2; ++i)
        #pragma unroll
        for (int j = 0; j < 2; ++j)
            #pragma unroll
            for (int r = 0; r < 16; ++r) acc[i][j][r] = 0.0f;

    // prologue: stage t=0 (seg0: acol=bcol=0) into buffer 0
    #pragma unroll
    for (int c = 0; c < 4; ++c) {
        gll16(Xc + aoff[c], (char*)As[0] + ldsb[c]);
        gll16(Wc + boff[c], (char*)Bs[0] + ldsb[c]);
    }

    for (int t = 0; t < 24; ++t) {
        int cur = t & 1;
        if (t < 23) {
            int tn  = t + 1;
            int tt  = tn & 7, seg = tn >> 3;
            int acol = tt * 64 + (seg == 2 ? 512 : 0);   // A-lo plane for seg 2
            int bcol = tt * 64 + (seg == 1 ? 512 : 0);   // B-lo plane for seg 1
            int nxt = cur ^ 1;
            #pragma unroll
            for (int c = 0; c < 4; ++c) {
                gll16(Xc + aoff[c] + acol, (char*)As[nxt] + ldsb[c]);
                gll16(Wc + boff[c] + bcol, (char*)Bs[nxt] + ldsb[c]);
            }
            // 16 outstanding; retire the 8 oldest (current buffer), keep 8 flying
            asm volatile("s_waitcnt vmcnt(8)" ::: "memory");
        } else {
            asm volatile("s_waitcnt vmcnt(0)" ::: "memory");
        }
        __builtin_amdgcn_s_barrier();                // all waves' cur-stage landed

        const char* Ab = (const char*)As[cur];
        const char* Bb = (const char*)Bs[cur];
        #pragma unroll
        for (int ks = 0; ks < 4; ++ks) {
            int kb = ks * 32 + kg * 16;              // byte offset in 128B row
            bf16x8 af[2], bb[2];
            #pragma unroll
            for (int f = 0; f < 2; ++f) {
                int ra = wm * 64 + f * 32 + lr;
                af[f] = *(const bf16x8*)(Ab + ra * 128 + (kb ^ ((ra & 7) << 4)));
                int rb = wn * 64 + f * 32 + lr;
                bb[f] = *(const bf16x8*)(Bb + rb * 128 + (kb ^ ((rb & 7) << 4)));
            }
            #pragma unroll
            for (int i = 0; i < 2; ++i)
                #pragma unroll
                for (int j = 0; j < 2; ++j)
                    acc[i][j] = __builtin_amdgcn_mfma_f32_32x32x16_bf16(af[i], bb[j], acc[i][j], 0, 0, 0);
        }
        asm volatile("" ::: "memory");               // LDS reads stay before barrier
        __builtin_amdgcn_s_barrier();                // reads done -> next DMA may write
    }

    // epilogue: col=lane&31, row=(r&3)+8*(r>>2)+4*(lane>>5)
    #pragma unroll
    for (int j = 0; j < 2; ++j) {
        int col = n0 + wn * 64 + j * 32 + lr;
        float bv = bias[col];
        #pragma unroll
        for (int i = 0; i < 2; ++i) {
            #pragma unroll
            for (int r = 0; r < 16; ++r) {
                int lm = wm * 64 + i * 32 + (r & 3) + 8 * (r >> 2) + 4 * kg;
                if (lm < rows)
                    out[(size_t)(row0 + lm) * D_N + col] = acc[i][j][r] + bv;
            }
        }
    }
}

// ---------------- round-1 fallback (used only if ws too small) ---------------
#define KPAD 72
__global__ void __launch_bounds__(256, 2)
grouped_gemm_fallback(const float* __restrict__ X, const float* __restrict__ W,
                      const float* __restrict__ bias, const int* __restrict__ cnt,
                      const int* __restrict__ desc, float* __restrict__ out) {
    extern __shared__ u16 lds[];
    u16* Ahi = lds;
    u16* Alo = Ahi + BM * KPAD;
    u16* Bhi = Alo + BM * KPAD;
    u16* Blo = Bhi + BM * KPAD;

    int bid = blockIdx.x;
    int s = (bid & 7) * (GRID_X / 8) + (bid >> 3);
    int tile  = s >> 2;
    int ntile = s & 3;
    if (tile >= cnt[0]) return;

    int expert = desc[3 * tile];
    int row0   = desc[3 * tile + 1];
    int rows   = desc[3 * tile + 2];
    int n0 = ntile * BN;

    const int tid  = threadIdx.x;
    const int lane = tid & 63;
    const int wid  = tid >> 6;
    const int wm = wid >> 1, wn = wid & 1;
    const int lr = lane & 31, kg = lane >> 5;

    const float* Wp = W + (size_t)expert * D_K * D_N;

    f32x16 acc[2][2];
    #pragma unroll
    for (int i = 0; i < 2; ++i)
        #pragma unroll
        for (int j = 0; j < 2; ++j)
            #pragma unroll
            for (int r = 0; r < 16; ++r) acc[i][j][r] = 0.0f;

    for (int kt = 0; kt < D_K / 64; ++kt) {
        int k0 = kt * 64;
        #pragma unroll
        for (int it = 0; it < 8; ++it) {
            int idx = it * 256 + tid;
            int m = idx >> 4, q = idx & 15;
            f32x4 v;
            if (m < rows) v = *(const f32x4*)(X + (size_t)(row0 + m) * D_K + k0 + q * 4);
            else          v[0] = v[1] = v[2] = v[3] = 0.0f;
            u32 h[4], l[4];
            #pragma unroll
            for (int j = 0; j < 4; ++j) cvt_split(v[j], h[j], l[j]);
            uint2 hp, lp;
            hp.x = h[0] | (h[1] << 16); hp.y = h[2] | (h[3] << 16);
            lp.x = l[0] | (l[1] << 16); lp.y = l[2] | (l[3] << 16);
            *(uint2*)(Ahi + m * KPAD + q * 4) = hp;
            *(uint2*)(Alo + m * KPAD + q * 4) = lp;
        }
        #pragma unroll
        for (int it = 0; it < 8; ++it) {
            int idx = it * 256 + tid;
            int n = idx & 127, kb = idx >> 7;
            const float* bp = Wp + (size_t)(k0 + kb * 4) * D_N + n0 + n;
            u32 h[4], l[4];
            #pragma unroll
            for (int j = 0; j < 4; ++j) { float b = bp[(size_t)j * D_N]; cvt_split(b, h[j], l[j]); }
            uint2 hp, lp;
            hp.x = h[0] | (h[1] << 16); hp.y = h[2] | (h[3] << 16);
            lp.x = l[0] | (l[1] << 16); lp.y = l[2] | (l[3] << 16);
            *(uint2*)(Bhi + n * KPAD + kb * 4) = hp;
            *(uint2*)(Blo + n * KPAD + kb * 4) = lp;
        }
        __syncthreads();
        #pragma unroll
        for (int ks = 0; ks < 4; ++ks) {
            bf16x8 ah[2], al[2], bh[2], bl[2];
            #pragma unroll
            for (int f = 0; f < 2; ++f) {
                int aoff2 = (wm * 64 + f * 32 + lr) * KPAD + ks * 16 + kg * 8;
                ah[f] = *(const bf16x8*)(Ahi + aoff2);
                al[f] = *(const bf16x8*)(Alo + aoff2);
                int boff2 = (wn * 64 + f * 32 + lr) * KPAD + ks * 16 + kg * 8;
                bh[f] = *(const bf16x8*)(Bhi + boff2);
                bl[f] = *(const bf16x8*)(Blo + boff2);
            }
            #pragma unroll
            for (int i = 0; i < 2; ++i)
                #pragma unroll
                for (int j = 0; j < 2; ++j) {
                    acc[i][j] = __builtin_amdgcn_mfma_f32_32x32x16_bf16(ah[i], bh[j], acc[i][j], 0, 0, 0);
                    acc[i][j] = __builtin_amdgcn_mfma_f32_32x32x16_bf16(ah[i], bl[j], acc[i][j], 0, 0, 0);
                    acc[i][j] = __builtin_amdgcn_mfma_f32_32x32x16_bf16(al[i], bh[j], acc[i][j], 0, 0, 0);
                }
        }
        __syncthreads();
    }
    #pragma unroll
    for (int j = 0; j < 2; ++j) {
        int col = n0 + wn * 64 + j * 32 + lr;
        float bv = bias[col];
        #pragma unroll
        for (int i = 0; i < 2; ++i) {
            #pragma unroll
            for (int r = 0; r < 16; ++r) {
                int lm = wm * 64 + i * 32 + (r & 3) + 8 * (r >> 2) + 4 * kg;
                if (lm < rows)
                    out[(size_t)(row0 + lm) * D_N + col] = acc[i][j][r] + bv;
            }
        }
    }
}

extern "C" void kernel_launch(void* const* d_in, const int* in_sizes, int n_in,
                              void* d_out, int out_size, void* d_ws, size_t ws_size,
                              hipStream_t stream) {
    const float* X    = (const float*)d_in[0];
    const float* W    = (const float*)d_in[1];
    const float* bias = (const float*)d_in[2];
    const int*   gs   = (const int*)d_in[3];
    float* out = (float*)d_out;

    int T = in_sizes[0] / D_K;                       // 65536

    int* cnt  = (int*)d_ws;
    int* desc = cnt + 4;                             // desc: 576*3*4 = 6912 B
    hipLaunchKernelGGL(build_tiles_kernel, dim3(1), dim3(64), 0, stream, gs, cnt, desc);

    size_t x_bytes = (size_t)T * 1024 * sizeof(u16);           // 128 MiB
    size_t w_bytes = (size_t)NUM_E * D_N * 1024 * sizeof(u16); // 64 MiB
    size_t need = 8192 + x_bytes + w_bytes;

    if (ws_size >= need) {
        u16* Xc = (u16*)((char*)d_ws + 8192);
        u16* Wc = (u16*)((char*)d_ws + 8192 + x_bytes);

        int nocts = T * (D_K / 8);
        hipLaunchKernelGGL(convert_x_kernel, dim3(2048), dim3(256), 0, stream, X, Xc, nocts);
        hipLaunchKernelGGL(convert_w_kernel, dim3(NUM_E * 64), dim3(256), 0, stream, W, Wc);
        hipLaunchKernelGGL(gemm_split_kernel, dim3(GRID_X), dim3(256), 0, stream,
                           Xc, Wc, bias, cnt, desc, out, T);
    } else {
        const size_t lds_bytes = (size_t)4 * BM * KPAD * sizeof(u16);
        hipLaunchKernelGGL(grouped_gemm_fallback, dim3(GRID_X), dim3(256), lds_bytes, stream,
                           X, W, bias, cnt, desc, out);
    }
}

// Round 8
// 458.086 us; speedup vs baseline: 1.0115x; 1.0115x over previous
//
#include <hip/hip_runtime.h>
#include <hip/hip_bf16.h>

#define NUM_E 64
#define D_K 512
#define D_N 512
#define BM 128
#define BN 128
#define MAX_TILES 576              // T/BM + E worst case
#define GRID_X (MAX_TILES * 4)     // 2304, divisible by 8 -> bijective XCD swizzle

typedef __bf16 bf16x8 __attribute__((ext_vector_type(8)));
typedef float f32x16 __attribute__((ext_vector_type(16)));
typedef float f32x4 __attribute__((ext_vector_type(4)));
typedef unsigned int u32;
typedef unsigned short u16;

__device__ __forceinline__ int imin(int a, int b) { return a < b ? a : b; }

// async global->LDS, 16B per lane. LDS dest must be wave-uniform base.
__device__ __forceinline__ void gll16(const void* g, void* l) {
    __builtin_amdgcn_global_load_lds(
        (const __attribute__((address_space(1))) u32*)(uintptr_t)g,
        (__attribute__((address_space(3))) u32*)(uintptr_t)l, 16, 0, 0);
}

// fp32 -> bf16 hi (round-nearest-even) + bf16 lo (truncated residual).
// IDENTICAL bits since round 1 (absmax 0.015625) — do not change.
__device__ __forceinline__ void cvt_split(float a, u32 &hi, u32 &lo) {
    u32 u  = __float_as_uint(a);
    u32 rh = (u + 0x7FFFu + ((u >> 16) & 1u)) & 0xFFFF0000u;
    hi = rh >> 16;
    float res = a - __uint_as_float(rh);
    lo = __float_as_uint(res) >> 16;
}

// ---------------- tile descriptors (no tile crosses a group boundary) -------
__global__ void build_tiles_kernel(const int* __restrict__ gs,
                                   int* __restrict__ cnt,
                                   int* __restrict__ desc) {
    int e = threadIdx.x;
    if (e >= NUM_E) return;
    int row = 0, toff = 0;
    for (int i = 0; i < e; ++i) {
        int g = gs[i];
        row += g;
        toff += (g + BM - 1) / BM;
    }
    int g = gs[e];
    int nt = (g + BM - 1) / BM;
    for (int i = 0; i < nt; ++i) {
        int b = 3 * (toff + i);
        desc[b]     = e;
        desc[b + 1] = row + i * BM;
        desc[b + 2] = imin(BM, g - i * BM);
    }
    if (e == NUM_E - 1) cnt[0] = toff + nt;
}

// ------- convert X: [T][512] f32 -> [T][1024] bf16 (hi | lo), 16B stores ----
__global__ void convert_x_kernel(const float* __restrict__ X, u16* __restrict__ Xc,
                                 int nocts) {
    int idx = blockIdx.x * blockDim.x + threadIdx.x;
    int stride = gridDim.x * blockDim.x;
    for (int o = idx; o < nocts; o += stride) {
        int row = o >> 6;            // 64 octs (of 8 floats) per 512-float row
        int c8  = (o & 63) * 8;
        const float* p = X + (size_t)o * 8;
        f32x4 v0 = *(const f32x4*)p;
        f32x4 v1 = *(const f32x4*)(p + 4);
        u32 h[8], l[8];
        #pragma unroll
        for (int j = 0; j < 4; ++j) cvt_split(v0[j], h[j], l[j]);
        #pragma unroll
        for (int j = 0; j < 4; ++j) cvt_split(v1[j], h[4 + j], l[4 + j]);
        uint4 hp, lp;
        hp.x = h[0] | (h[1] << 16); hp.y = h[2] | (h[3] << 16);
        hp.z = h[4] | (h[5] << 16); hp.w = h[6] | (h[7] << 16);
        lp.x = l[0] | (l[1] << 16); lp.y = l[2] | (l[3] << 16);
        lp.z = l[4] | (l[5] << 16); lp.w = l[6] | (l[7] << 16);
        *(uint4*)(Xc + (size_t)row * 1024 + c8)       = hp;
        *(uint4*)(Xc + (size_t)row * 1024 + 512 + c8) = lp;
    }
}

// -- convert+transpose W: [e][k][n] f32 -> [e][n][1024] bf16 (hi | lo) -------
__global__ void convert_w_kernel(const float* __restrict__ W, u16* __restrict__ Wc) {
    __shared__ float Tf[64 * 68];    // [n][k], stride 68
    int bid = blockIdx.x;            // 64e x 8ti x 8tj = 4096
    int e  = bid >> 6;
    int ti = (bid >> 3) & 7;         // k-block
    int tj = bid & 7;                // n-block
    int tid = threadIdx.x;

    const float* Wp = W + (size_t)e * D_K * D_N + (size_t)(ti * 64) * D_N + tj * 64;
    #pragma unroll
    for (int it = 0; it < 4; ++it) {
        int kl = it * 16 + (tid >> 4);       // 0..63
        int nl = (tid & 15) * 4;             // 0..60
        f32x4 v = *(const f32x4*)(Wp + (size_t)kl * D_N + nl);
        #pragma unroll
        for (int j = 0; j < 4; ++j) Tf[(nl + j) * 68 + kl] = v[j];
    }
    __syncthreads();
    #pragma unroll
    for (int it = 0; it < 2; ++it) {
        int nl = it * 32 + (tid >> 3);       // 0..63
        int ko = (tid & 7) * 8;              // 0..56, 8 k's each
        f32x4 a = *(const f32x4*)(Tf + nl * 68 + ko);
        f32x4 b = *(const f32x4*)(Tf + nl * 68 + ko + 4);
        u32 h[8], l[8];
        #pragma unroll
        for (int j = 0; j < 4; ++j) cvt_split(a[j], h[j], l[j]);
        #pragma unroll
        for (int j = 0; j < 4; ++j) cvt_split(b[j], h[4 + j], l[4 + j]);
        uint4 hp, lp;
        hp.x = h[0] | (h[1] << 16); hp.y = h[2] | (h[3] << 16);
        hp.z = h[4] | (h[5] << 16); hp.w = h[6] | (h[7] << 16);
        lp.x = l[0] | (l[1] << 16); lp.y = l[2] | (l[3] << 16);
        lp.z = l[4] | (l[5] << 16); lp.w = l[6] | (l[7] << 16);
        u16* outp = Wc + ((size_t)e << 19) + (size_t)(tj * 64 + nl) * 1024 + ti * 64 + ko;
        *(uint4*)outp         = hp;
        *(uint4*)(outp + 512) = lp;
    }
}

// -- main GEMM: co-staged hi/lo planes, 8 K-chunks of 64, all 3 passes from
//    one staging. LDS rows are 256B ([hi 128B | lo 128B]) -> full 16-slot XOR
//    swizzle (conflict-free); read:MFMA = 8:12 per ks vs 1:1 before. ---------
__global__ void __launch_bounds__(256, 2)
gemm_split_kernel(const u16* __restrict__ Xc, const u16* __restrict__ Wc,
                  const float* __restrict__ bias, const int* __restrict__ cnt,
                  const int* __restrict__ desc, float* __restrict__ out, int T) {
    __shared__ u16 As[BM * 128];   // 32 KB: 128 rows x 256B (hi|lo, swizzled)
    __shared__ u16 Bs[BN * 128];   // 32 KB

    int bid = blockIdx.x;
    int s = (bid & 7) * (GRID_X / 8) + (bid >> 3);   // bijective XCD swizzle
    int tile  = s >> 2;
    int ntile = s & 3;
    if (tile >= cnt[0]) return;

    int expert = desc[3 * tile];
    int row0   = desc[3 * tile + 1];
    int rows   = desc[3 * tile + 2];
    int n0 = ntile * BN;

    const int tid  = threadIdx.x;
    const int lane = tid & 63;
    const int wid  = tid >> 6;
    const int wm = wid >> 1, wn = wid & 1;
    const int lr = lane & 31, kg = lane >> 5;

    // Staging: chunk = c*256+tid; r = chunk>>4; j = chunk&15 (16 x 16B = 256B/row).
    // LDS linear; SOURCE position XOR-swizzled within the virtual 256B row
    // (v<128 -> hi-plane byte v; v>=128 -> lo-plane byte v-128). Rule #21:
    // same involution applied on the read side.
    int aoff[8], boff[8], ldsb[8];
    #pragma unroll
    for (int c = 0; c < 8; ++c) {
        int chunk = c * 256 + tid;
        int r = chunk >> 4, j = chunk & 15;
        int cb = (j * 16) ^ ((r & 15) << 4);         // virtual byte in 256B row
        int inrow = (cb < 128) ? (cb >> 1) : (512 + ((cb - 128) >> 1));  // u16
        int ar = imin(row0 + r, T - 1);              // clamp (padded tail rows)
        aoff[c] = ar * 1024 + inrow;
        boff[c] = (expert << 19) + (n0 + r) * 1024 + inrow;
        ldsb[c] = (c * 256 + wid * 64) * 16;         // wave-uniform byte base
    }

    f32x16 acc[2][2];
    #pragma unroll
    for (int i = 0; i < 2; ++i)
        #pragma unroll
        for (int j = 0; j < 2; ++j)
            #pragma unroll
            for (int r = 0; r < 16; ++r) acc[i][j][r] = 0.0f;

    for (int kc = 0; kc < 8; ++kc) {
        int ksrc = kc * 64;                          // both planes advance 64 u16
        #pragma unroll
        for (int c = 0; c < 8; ++c) {
            gll16(Xc + aoff[c] + ksrc, (char*)As + ldsb[c]);
            gll16(Wc + boff[c] + ksrc, (char*)Bs + ldsb[c]);
        }
        __syncthreads();                             // staged data visible

        #pragma unroll
        for (int ks = 0; ks < 4; ++ks) {
            int kb = ks * 32 + kg * 16;              // hi-plane byte in [0,128)
            bf16x8 ah[2], al[2], bh[2], bl[2];
            #pragma unroll
            for (int f = 0; f < 2; ++f) {
                int ra = wm * 64 + f * 32 + lr;
                int swa = (ra & 15) << 4;
                ah[f] = *(const bf16x8*)((const char*)As + ra * 256 + (kb ^ swa));
                al[f] = *(const bf16x8*)((const char*)As + ra * 256 + ((128 | kb) ^ swa));
                int rb = wn * 64 + f * 32 + lr;
                int swb = (rb & 15) << 4;
                bh[f] = *(const bf16x8*)((const char*)Bs + rb * 256 + (kb ^ swb));
                bl[f] = *(const bf16x8*)((const char*)Bs + rb * 256 + ((128 | kb) ^ swb));
            }
            #pragma unroll
            for (int i = 0; i < 2; ++i)
                #pragma unroll
                for (int j = 0; j < 2; ++j) {
                    acc[i][j] = __builtin_amdgcn_mfma_f32_32x32x16_bf16(ah[i], bh[j], acc[i][j], 0, 0, 0);
                    acc[i][j] = __builtin_amdgcn_mfma_f32_32x32x16_bf16(ah[i], bl[j], acc[i][j], 0, 0, 0);
                    acc[i][j] = __builtin_amdgcn_mfma_f32_32x32x16_bf16(al[i], bh[j], acc[i][j], 0, 0, 0);
                }
        }
        __syncthreads();                             // reads done -> next DMA ok
    }

    // epilogue: col=lane&31, row=(r&3)+8*(r>>2)+4*(lane>>5)
    #pragma unroll
    for (int j = 0; j < 2; ++j) {
        int col = n0 + wn * 64 + j * 32 + lr;
        float bv = bias[col];
        #pragma unroll
        for (int i = 0; i < 2; ++i) {
            #pragma unroll
            for (int r = 0; r < 16; ++r) {
                int lm = wm * 64 + i * 32 + (r & 3) + 8 * (r >> 2) + 4 * kg;
                if (lm < rows)
                    out[(size_t)(row0 + lm) * D_N + col] = acc[i][j][r] + bv;
            }
        }
    }
}

// ---------------- round-1 fallback (used only if ws too small) ---------------
#define KPAD 72
__global__ void __launch_bounds__(256, 2)
grouped_gemm_fallback(const float* __restrict__ X, const float* __restrict__ W,
                      const float* __restrict__ bias, const int* __restrict__ cnt,
                      const int* __restrict__ desc, float* __restrict__ out) {
    extern __shared__ u16 lds[];
    u16* Ahi = lds;
    u16* Alo = Ahi + BM * KPAD;
    u16* Bhi = Alo + BM * KPAD;
    u16* Blo = Bhi + BM * KPAD;

    int bid = blockIdx.x;
    int s = (bid & 7) * (GRID_X / 8) + (bid >> 3);
    int tile  = s >> 2;
    int ntile = s & 3;
    if (tile >= cnt[0]) return;

    int expert = desc[3 * tile];
    int row0   = desc[3 * tile + 1];
    int rows   = desc[3 * tile + 2];
    int n0 = ntile * BN;

    const int tid  = threadIdx.x;
    const int lane = tid & 63;
    const int wid  = tid >> 6;
    const int wm = wid >> 1, wn = wid & 1;
    const int lr = lane & 31, kg = lane >> 5;

    const float* Wp = W + (size_t)expert * D_K * D_N;

    f32x16 acc[2][2];
    #pragma unroll
    for (int i = 0; i < 2; ++i)
        #pragma unroll
        for (int j = 0; j < 2; ++j)
            #pragma unroll
            for (int r = 0; r < 16; ++r) acc[i][j][r] = 0.0f;

    for (int kt = 0; kt < D_K / 64; ++kt) {
        int k0 = kt * 64;
        #pragma unroll
        for (int it = 0; it < 8; ++it) {
            int idx = it * 256 + tid;
            int m = idx >> 4, q = idx & 15;
            f32x4 v;
            if (m < rows) v = *(const f32x4*)(X + (size_t)(row0 + m) * D_K + k0 + q * 4);
            else          v[0] = v[1] = v[2] = v[3] = 0.0f;
            u32 h[4], l[4];
            #pragma unroll
            for (int j = 0; j < 4; ++j) cvt_split(v[j], h[j], l[j]);
            uint2 hp, lp;
            hp.x = h[0] | (h[1] << 16); hp.y = h[2] | (h[3] << 16);
            lp.x = l[0] | (l[1] << 16); lp.y = l[2] | (l[3] << 16);
            *(uint2*)(Ahi + m * KPAD + q * 4) = hp;
            *(uint2*)(Alo + m * KPAD + q * 4) = lp;
        }
        #pragma unroll
        for (int it = 0; it < 8; ++it) {
            int idx = it * 256 + tid;
            int n = idx & 127, kb = idx >> 7;
            const float* bp = Wp + (size_t)(k0 + kb * 4) * D_N + n0 + n;
            u32 h[4], l[4];
            #pragma unroll
            for (int j = 0; j < 4; ++j) { float b = bp[(size_t)j * D_N]; cvt_split(b, h[j], l[j]); }
            uint2 hp, lp;
            hp.x = h[0] | (h[1] << 16); hp.y = h[2] | (h[3] << 16);
            lp.x = l[0] | (l[1] << 16); lp.y = l[2] | (l[3] << 16);
            *(uint2*)(Bhi + n * KPAD + kb * 4) = hp;
            *(uint2*)(Blo + n * KPAD + kb * 4) = lp;
        }
        __syncthreads();
        #pragma unroll
        for (int ks = 0; ks < 4; ++ks) {
            bf16x8 ah[2], al[2], bh[2], bl[2];
            #pragma unroll
            for (int f = 0; f < 2; ++f) {
                int aoff2 = (wm * 64 + f * 32 + lr) * KPAD + ks * 16 + kg * 8;
                ah[f] = *(const bf16x8*)(Ahi + aoff2);
                al[f] = *(const bf16x8*)(Alo + aoff2);
                int boff2 = (wn * 64 + f * 32 + lr) * KPAD + ks * 16 + kg * 8;
                bh[f] = *(const bf16x8*)(Bhi + boff2);
                bl[f] = *(const bf16x8*)(Blo + boff2);
            }
            #pragma unroll
            for (int i = 0; i < 2; ++i)
                #pragma unroll
                for (int j = 0; j < 2; ++j) {
                    acc[i][j] = __builtin_amdgcn_mfma_f32_32x32x16_bf16(ah[i], bh[j], acc[i][j], 0, 0, 0);
                    acc[i][j] = __builtin_amdgcn_mfma_f32_32x32x16_bf16(ah[i], bl[j], acc[i][j], 0, 0, 0);
                    acc[i][j] = __builtin_amdgcn_mfma_f32_32x32x16_bf16(al[i], bh[j], acc[i][j], 0, 0, 0);
                }
        }
        __syncthreads();
    }
    #pragma unroll
    for (int j = 0; j < 2; ++j) {
        int col = n0 + wn * 64 + j * 32 + lr;
        float bv = bias[col];
        #pragma unroll
        for (int i = 0; i < 2; ++i) {
            #pragma unroll
            for (int r = 0; r < 16; ++r) {
                int lm = wm * 64 + i * 32 + (r & 3) + 8 * (r >> 2) + 4 * kg;
                if (lm < rows)
                    out[(size_t)(row0 + lm) * D_N + col] = acc[i][j][r] + bv;
            }
        }
    }
}

extern "C" void kernel_launch(void* const* d_in, const int* in_sizes, int n_in,
                              void* d_out, int out_size, void* d_ws, size_t ws_size,
                              hipStream_t stream) {
    const float* X    = (const float*)d_in[0];
    const float* W    = (const float*)d_in[1];
    const float* bias = (const float*)d_in[2];
    const int*   gs   = (const int*)d_in[3];
    float* out = (float*)d_out;

    int T = in_sizes[0] / D_K;                       // 65536

    int* cnt  = (int*)d_ws;
    int* desc = cnt + 4;                             // desc: 576*3*4 = 6912 B
    hipLaunchKernelGGL(build_tiles_kernel, dim3(1), dim3(64), 0, stream, gs, cnt, desc);

    size_t x_bytes = (size_t)T * 1024 * sizeof(u16);           // 128 MiB
    size_t w_bytes = (size_t)NUM_E * D_N * 1024 * sizeof(u16); // 64 MiB
    size_t need = 8192 + x_bytes + w_bytes;

    if (ws_size >= need) {
        u16* Xc = (u16*)((char*)d_ws + 8192);
        u16* Wc = (u16*)((char*)d_ws + 8192 + x_bytes);

        int nocts = T * (D_K / 8);
        hipLaunchKernelGGL(convert_x_kernel, dim3(2048), dim3(256), 0, stream, X, Xc, nocts);
        hipLaunchKernelGGL(convert_w_kernel, dim3(NUM_E * 64), dim3(256), 0, stream, W, Wc);
        hipLaunchKernelGGL(gemm_split_kernel, dim3(GRID_X), dim3(256), 0, stream,
                           Xc, Wc, bias, cnt, desc, out, T);
    } else {
        const size_t lds_bytes = (size_t)4 * BM * KPAD * sizeof(u16);
        hipLaunchKernelGGL(grouped_gemm_fallback, dim3(GRID_X), dim3(256), lds_bytes, stream,
                           X, W, bias, cnt, desc, out);
    }
}